// Round 5
// baseline (209.774 us; speedup 1.0000x reference)
//
#include <hip/hip_runtime.h>
#include <math.h>

#define BB 16
#define HH 256
#define WW 256
#define NN (BB*HH*WW)
#define STH 4   // sobel rows per block

static __device__ constexpr float INF_EDT = 131072.0f; // H*H + W*W, exact in fp32

__device__ __forceinline__ float sigmoidf(float v){ return 1.0f/(1.0f+expf(-v)); }
// stable log_sigmoid(v) = min(v,0) - log1p(exp(-|v|))
__device__ __forceinline__ float logsigf(float v){
  return fminf(v, 0.0f) - log1pf(expf(-fabsf(v)));
}
__device__ __forceinline__ float min3f(float a, float b, float c){
  return fminf(fminf(a, b), c);   // clang fuses to v_min3_f32
}

__global__ void init_ws_k(float* __restrict__ acc, int* __restrict__ has_pos){
  int t = threadIdx.x;
  if (t < 8)  acc[t] = 0.0f;
  if (t < BB) has_pos[t] = 0;
}

// -------------------------------------------------------------------------
// Min-plus transform: out(x) = min_i [ f(i) + (x-i)^2 ]
//                            = x^2 + min_i [ (f(i)+i^2) - 2*i*x ]
// Integer-valued fp32 (< 2^24) -> bit-identical to the brute force reference.
// Candidate range split across 2 waves per line (min is associative ->
// exactness preserved); partials combined via LDS. 8 independent chains per
// thread; all LDS reads are wave-uniform broadcasts, writes are b128-linear.
// -------------------------------------------------------------------------

#define EDT_STEP(acc, xx, vv) \
  acc = min3f(acc, fmaf(m0,xx,vv.x), fmaf(m1,xx,vv.y)); \
  acc = min3f(acc, fmaf(m2,xx,vv.z), fmaf(m3,xx,vv.w))

// Pass 1: per (b, column j): g(x,j) = min_i f(i,j) + (x-i)^2
// Block = 512 thr (8 waves), 4 columns; wave w: col = w>>1, half = w&1.
// gA: seeds = pos (t>0.5) -> feeds d_in ; gB: seeds = ~pos -> feeds d_out
__global__ __launch_bounds__(512) void edt_pass1(const float* __restrict__ tgt,
                                                 float* __restrict__ gA,
                                                 float* __restrict__ gB,
                                                 int* __restrict__ has_pos){
  __shared__ __align__(16) float hp[4][HH];
  __shared__ __align__(16) float hn[4][HH];
  __shared__ float part[2][4][8][64];   // [half][col][set*4+k][lane]
  const int b  = blockIdx.x >> 6;
  const int j0 = (blockIdx.x & 63) << 2;
  const int t  = threadIdx.x;

  if (t < HH){
    // stage: thread t = row i, 4 consecutive columns as float4
    const float4 tv = *(const float4*)&tgt[(b*HH + t)*WW + j0];
    const float i2 = (float)t * (float)t;
    hp[0][t] = (tv.x>0.5f ? 0.0f : INF_EDT) + i2;
    hn[0][t] = (tv.x>0.5f ? INF_EDT : 0.0f) + i2;
    hp[1][t] = (tv.y>0.5f ? 0.0f : INF_EDT) + i2;
    hn[1][t] = (tv.y>0.5f ? INF_EDT : 0.0f) + i2;
    hp[2][t] = (tv.z>0.5f ? 0.0f : INF_EDT) + i2;
    hn[2][t] = (tv.z>0.5f ? INF_EDT : 0.0f) + i2;
    hp[3][t] = (tv.w>0.5f ? 0.0f : INF_EDT) + i2;
    hn[3][t] = (tv.w>0.5f ? INF_EDT : 0.0f) + i2;
    const bool anyp = (tv.x>0.5f)||(tv.y>0.5f)||(tv.z>0.5f)||(tv.w>0.5f);
    unsigned long long bal = __ballot(anyp);
    if ((t & 63) == 0 && bal) atomicOr(&has_pos[b], 1);
  }
  __syncthreads();

  const int w = t >> 6, l = t & 63;
  const int col = w >> 1, half = w & 1;
  const float x0 = (float)l, x1 = (float)(l+64), x2 = (float)(l+128), x3 = (float)(l+192);
  float ap0=3.4e38f, ap1=3.4e38f, ap2=3.4e38f, ap3=3.4e38f;
  float an0=3.4e38f, an1=3.4e38f, an2=3.4e38f, an3=3.4e38f;
  const float4* hp4 = (const float4*)hp[col];
  const float4* hn4 = (const float4*)hn[col];
  const int it0 = half << 5;              // 32 iters = 128 candidates per half
  float mjb = -8.0f * (float)it0;         // m0 = -2*(4*it)
  #pragma unroll 4
  for (int it = it0; it < it0 + 32; ++it){
    float4 vp = hp4[it];                  // wave-uniform broadcast reads
    float4 vn = hn4[it];
    float m0 = mjb, m1 = mjb-2.0f, m2 = mjb-4.0f, m3 = mjb-6.0f;
    EDT_STEP(ap0, x0, vp); EDT_STEP(ap1, x1, vp);
    EDT_STEP(ap2, x2, vp); EDT_STEP(ap3, x3, vp);
    EDT_STEP(an0, x0, vn); EDT_STEP(an1, x1, vn);
    EDT_STEP(an2, x2, vn); EDT_STEP(an3, x3, vn);
    mjb -= 8.0f;
  }
  {
    float* pp = &part[half][col][0][l];
    pp[0*64]=ap0; pp[1*64]=ap1; pp[2*64]=ap2; pp[3*64]=ap3;
    pp[4*64]=an0; pp[5*64]=an1; pp[6*64]=an2; pp[7*64]=an3;
  }
  __syncthreads();

  // combine halves + add x^2 + write: 1024 outputs, 2 per thread
  #pragma unroll
  for (int pi = 0; pi < 2; ++pi){
    const int p = t + pi*512;
    const int c = p >> 8, x = p & 255, k = x >> 6, ll = x & 63;
    const float xf = (float)x;
    const float ap = fminf(part[0][c][k  ][ll], part[1][c][k  ][ll]) + xf*xf;
    const float an = fminf(part[0][c][4+k][ll], part[1][c][4+k][ll]) + xf*xf;
    const int o = b*HH*WW + x*WW + j0 + c;
    gA[o] = ap; gB[o] = an;
  }
}

// Pass 2: per (b, row x): d2(x,y) = min_j g(x,j) + (y-j)^2 ; fused focal/ce/boundary.
// Block = 256 thr (4 waves), 2 rows; wave w: line = w>>1, half = w&1.
__global__ __launch_bounds__(256) void edt_pass2_fused(const float* __restrict__ inp,
    const float* __restrict__ tgt, const float* __restrict__ gA, const float* __restrict__ gB,
    const int* __restrict__ has_pos, float* __restrict__ acc){
  __shared__ __align__(16) float ha[2][WW];
  __shared__ __align__(16) float hb[2][WW];
  __shared__ float part[2][2][8][64];   // [half][line][set*4+k][lane]
  __shared__ float red[3][4];
  const int b  = blockIdx.x >> 7;
  const int x0 = (blockIdx.x & 127) << 1;
  const int t  = threadIdx.x;

  // stage h(j) = g(j) + j^2 as float4 (ds_write_b128, linear -> conflict-free)
  {
    const int q = t >> 6, l = t & 63;
    const int r = q >> 1, isB = q & 1;
    const float jf = (float)(4*l);
    const int base = (b*HH + x0 + r)*WW + 4*l;
    const float4 v = isB ? *(const float4*)&gB[base] : *(const float4*)&gA[base];
    float4 h;
    h.x = v.x + jf*jf;            h.y = v.y + (jf+1.0f)*(jf+1.0f);
    h.z = v.z + (jf+2.0f)*(jf+2.0f); h.w = v.w + (jf+3.0f)*(jf+3.0f);
    if (isB) *(float4*)&hb[r][4*l] = h; else *(float4*)&ha[r][4*l] = h;
  }
  __syncthreads();

  const int w = t >> 6, l = t & 63;
  const int line = w >> 1, half = w & 1;
  const float y0 = (float)l, y1 = (float)(l+64), y2 = (float)(l+128), y3 = (float)(l+192);
  float dp0=3.4e38f, dp1=3.4e38f, dp2=3.4e38f, dp3=3.4e38f;
  float dn0=3.4e38f, dn1=3.4e38f, dn2=3.4e38f, dn3=3.4e38f;
  const float4* ha4 = (const float4*)ha[line];
  const float4* hb4 = (const float4*)hb[line];
  const int it0 = half << 5;
  float mjb = -8.0f * (float)it0;
  #pragma unroll 4
  for (int it = it0; it < it0 + 32; ++it){
    float4 va = ha4[it];
    float4 vb = hb4[it];
    float m0 = mjb, m1 = mjb-2.0f, m2 = mjb-4.0f, m3 = mjb-6.0f;
    EDT_STEP(dp0, y0, va); EDT_STEP(dp1, y1, va);
    EDT_STEP(dp2, y2, va); EDT_STEP(dp3, y3, va);
    EDT_STEP(dn0, y0, vb); EDT_STEP(dn1, y1, vb);
    EDT_STEP(dn2, y2, vb); EDT_STEP(dn3, y3, vb);
    mjb -= 8.0f;
  }
  {
    float* pp = &part[half][line][0][l];
    pp[0*64]=dp0; pp[1*64]=dp1; pp[2*64]=dp2; pp[3*64]=dp3;
    pp[4*64]=dn0; pp[5*64]=dn1; pp[6*64]=dn2; pp[7*64]=dn3;
  }
  __syncthreads();

  // combine halves + fused epilogue: 512 pixels, 2 per thread
  const int hp_ = has_pos[b];
  float s0 = 0.0f, s1 = 0.0f, s2 = 0.0f;   // focal, bce, boundary
  #pragma unroll
  for (int pi = 0; pi < 2; ++pi){
    const int p = t + pi*256;
    const int ln2 = p >> 8, y = p & 255, k = y >> 6, ll = y & 63;
    const float yf = (float)y;
    const float dp = fminf(part[0][ln2][k  ][ll], part[1][ln2][k  ][ll]) + yf*yf;
    const float dn = fminf(part[0][ln2][4+k][ll], part[1][ln2][4+k][ll]) + yf*yf;
    const int o = (b*HH + x0 + ln2)*WW + y;
    const float xv = inp[o];
    const float tv = tgt[o];
    const float sg = sigmoidf(xv);
    float sdf = sqrtf(dn) - sqrtf(dp);     // d_out - d_in
    sdf = hp_ ? sdf : 0.0f;
    s2 += (sg - tv) * sdf;
    const float lp = logsigf(xv);
    const float ln = logsigf(-xv);
    const float bce = -(tv*lp + (1.0f - tv)*ln);
    const float pt = expf(-bce);
    const float om = 1.0f - pt;
    s0 += 0.8f * om * om * bce;            // ALPHA=0.8, GAMMA=2
    s1 += bce;                             // ce with POS_W=1 == bce
  }
  #pragma unroll
  for (int o = 32; o > 0; o >>= 1){
    s0 += __shfl_down(s0, o);
    s1 += __shfl_down(s1, o);
    s2 += __shfl_down(s2, o);
  }
  if (l == 0){ red[0][w]=s0; red[1][w]=s1; red[2][w]=s2; }
  __syncthreads();
  if (t == 0){
    atomicAdd(&acc[0], red[0][0]+red[0][1]+red[0][2]+red[0][3]);
    atomicAdd(&acc[1], red[1][0]+red[1][1]+red[1][2]+red[1][3]);
    atomicAdd(&acc[2], red[2][0]+red[2][1]+red[2][2]+red[2][3]);
  }
}

// Sobel edge term: mean |S(sigmoid(x)) - S(t)| with replicate padding.
__global__ __launch_bounds__(256) void sobel_edge_k(const float* __restrict__ inp,
    const float* __restrict__ tgt, float* __restrict__ acc){
  __shared__ __align__(16) float ss[STH+2][WW];
  __shared__ __align__(16) float tt[STH+2][WW];
  __shared__ float red[4];
  const int b  = blockIdx.x >> 6;            // H/STH = 64 strips per image
  const int r0 = (blockIdx.x & 63) * STH;
  const int t  = threadIdx.x;
  const int g = t >> 6, l = t & 63;

  for (int k = g; k < STH+2; k += 4){
    int gr = r0 - 1 + k; gr = gr < 0 ? 0 : (gr > HH-1 ? HH-1 : gr);
    const float4 xv = *(const float4*)&inp[(b*HH + gr)*WW + 4*l];
    const float4 tv = *(const float4*)&tgt[(b*HH + gr)*WW + 4*l];
    float4 sv; sv.x = sigmoidf(xv.x); sv.y = sigmoidf(xv.y);
    sv.z = sigmoidf(xv.z); sv.w = sigmoidf(xv.w);
    *(float4*)&ss[k][4*l] = sv;
    *(float4*)&tt[k][4*l] = tv;
  }
  __syncthreads();

  const int c = t;
  const int cm = c ? c-1 : 0, cp = c < WW-1 ? c+1 : WW-1;
  float a0m = ss[0][cm], a0c = ss[0][c], a0p = ss[0][cp];
  float a1m = ss[1][cm], a1c = ss[1][c], a1p = ss[1][cp];
  float b0m = tt[0][cm], b0c = tt[0][c], b0p = tt[0][cp];
  float b1m = tt[1][cm], b1c = tt[1][c], b1p = tt[1][cp];
  float v = 0.0f;
  #pragma unroll
  for (int rr = 0; rr < STH; ++rr){
    const float a2m = ss[rr+2][cm], a2c = ss[rr+2][c], a2p = ss[rr+2][cp];
    const float b2m = tt[rr+2][cm], b2c = tt[rr+2][c], b2p = tt[rr+2][cp];
    const float gxs = ((a0p-a0m) + 2.0f*(a1p-a1m) + (a2p-a2m)) * 0.125f;
    const float gys = ((a2m-a0m) + 2.0f*(a2c-a0c) + (a2p-a0p)) * 0.125f;
    const float mags = sqrtf(gxs*gxs + gys*gys + 1e-6f);
    const float gxt = ((b0p-b0m) + 2.0f*(b1p-b1m) + (b2p-b2m)) * 0.125f;
    const float gyt = ((b2m-b0m) + 2.0f*(b2c-b0c) + (b2p-b0p)) * 0.125f;
    const float magt = sqrtf(gxt*gxt + gyt*gyt + 1e-6f);
    v += fabsf(mags - magt);
    a0m=a1m; a0c=a1c; a0p=a1p; a1m=a2m; a1c=a2c; a1p=a2p;
    b0m=b1m; b0c=b1c; b0p=b1p; b1m=b2m; b1c=b2c; b1p=b2p;
  }
  #pragma unroll
  for (int o = 32; o > 0; o >>= 1) v += __shfl_down(v, o);
  if (l == 0) red[g] = v;
  __syncthreads();
  if (t == 0) atomicAdd(&acc[3], red[0]+red[1]+red[2]+red[3]);
}

__global__ void finalize_k(const float* __restrict__ acc, float* __restrict__ out){
  out[0] = (acc[0] + acc[1] + acc[2] + acc[3]) * (1.0f/(float)NN);
}

extern "C" void kernel_launch(void* const* d_in, const int* in_sizes, int n_in,
                              void* d_out, int out_size, void* d_ws, size_t ws_size,
                              hipStream_t stream){
  const float* inp = (const float*)d_in[0];
  const float* tgt = (const float*)d_in[1];
  float* out = (float*)d_out;
  float* gA  = (float*)d_ws;          // B*H*W fp32, seeds = pos
  float* gB  = gA + NN;               // B*H*W fp32, seeds = ~pos
  float* acc = gB + NN;               // [focal, ce(bce), boundary, edge]
  int* has_pos = (int*)(acc + 8);     // B ints

  init_ws_k<<<1, 64, 0, stream>>>(acc, has_pos);
  edt_pass1<<<BB*(WW/4), 512, 0, stream>>>(tgt, gA, gB, has_pos);
  edt_pass2_fused<<<BB*(HH/2), 256, 0, stream>>>(inp, tgt, gA, gB, has_pos, acc);
  sobel_edge_k<<<BB*(HH/STH), 256, 0, stream>>>(inp, tgt, acc);
  finalize_k<<<1, 1, 0, stream>>>(acc, out);
}